// Round 25
// baseline (453.736 us; speedup 1.0000x reference)
//
#include <hip/hip_runtime.h>

#define T_   256
#define F_   32
#define NBB  8      // batches per block (fragment cols 8-15 duplicate) -> 512 blocks
#define TPB  384    // 6 waves: 0-3 L1 (gate-colocated), 4-5 L2 (gate-colocated) + x
#define IMW  136    // merged image row: [x(32)|h1(64)|h2(32)|pad(8)] ushorts

typedef __attribute__((ext_vector_type(8))) short bf16x8;
typedef __attribute__((ext_vector_type(4))) float f32x4;
typedef __attribute__((ext_vector_type(4))) unsigned short ush4;

#define K1f  (-1.44269504f)   // -log2(e)   : sigmoid gates
#define K2f  (-2.88539008f)   // -2*log2(e) : tanh gate & tanh(c)

__device__ __forceinline__ unsigned short bf16_rne(float x){
    unsigned u = __float_as_uint(x);
    u += 0x7FFF + ((u >> 16) & 1);
    return (unsigned short)(u >> 16);
}
__device__ __forceinline__ void bf16_split(float x, unsigned short& h, unsigned short& l){
    h = bf16_rne(x);
    float xr = __uint_as_float(((unsigned)h) << 16);
    l = bf16_rne(x - xr);
}
__device__ __forceinline__ void make_frags_s(const float* __restrict__ p8, float s,
                                             bf16x8& fh, bf16x8& fl){
    #pragma unroll
    for (int e = 0; e < 8; ++e){
        unsigned short h, l; bf16_split(s * p8[e], h, l);
        fh[e] = (short)h; fl[e] = (short)l;
    }
}
__device__ __forceinline__ float sigm_pre(float p){   // p = -log2e*x
    return __builtin_amdgcn_rcpf(1.f + __builtin_amdgcn_exp2f(p));
}
__device__ __forceinline__ float tanh_pre(float p){   // p = -2log2e*x
    return fmaf(2.f, __builtin_amdgcn_rcpf(1.f + __builtin_amdgcn_exp2f(p)), -1.f);
}
__device__ __forceinline__ float unit_combine(float gi, float gf, float gg, float go, float& c){
    const float i_ = sigm_pre(gi);
    const float f_ = sigm_pre(gf);
    const float g_ = tanh_pre(gg);
    const float o_ = sigm_pre(go);
    c = fmaf(f_, c, i_ * g_);
    return o_ * tanh_pre(K2f * c);
}

#define MFMA(A,B,C) __builtin_amdgcn_mfma_f32_16x16x32_bf16((A),(B),(C),0,0,0)

// LDS-visibility barrier WITHOUT vmcnt drain (x loads stay in flight).
__device__ __forceinline__ void step_barrier(){
    asm volatile("s_waitcnt lgkmcnt(0)" ::: "memory");
    __builtin_amdgcn_s_barrier();
}

// waves_per_eu(3,3): cap ~170 regs/wave (need ~155), pins 3 waves/SIMD so TWO
// 6-wave blocks co-reside per CU -> independent barrier domains fill stalls.
__global__ __launch_bounds__(TPB) __attribute__((amdgpu_waves_per_eu(3, 3)))
void lstm_mfma(
    const float* __restrict__ x,      // [4096,256,32]
    const float* __restrict__ W_ih1,  // [256,32]
    const float* __restrict__ W_hh1,  // [256,64]
    const float* __restrict__ b_ih1,  // [256]
    const float* __restrict__ b_hh1,  // [256]
    const float* __restrict__ W_ih2,  // [128,64]
    const float* __restrict__ W_hh2,  // [128,32]
    const float* __restrict__ b_ih2,  // [128]
    const float* __restrict__ b_hh2,  // [128]
    const float* __restrict__ W_fc1,  // [16,32]
    const float* __restrict__ b_fc1,  // [16]
    const float* __restrict__ W_fc2,  // [1,16]
    const float* __restrict__ b_fc2,  // [1]
    float* __restrict__ out)          // [4096]
{
    const int tid  = threadIdx.x;
    const int lane = tid & 63;
    const int wid  = tid >> 6;        // 0..5
    const int bb   = lane & 15;       // fragment row (A) / col (B)
    const int bbm  = bb & 7;          // B-col -> real batch (8-15 duplicate)
    const int kg   = (lane >> 4) & 3; // k-group of 8
    const int b0   = blockIdx.x * NBB;

    // merged image [x(32)|h1(64)|h2(32)|pad], double-buffered
    __shared__ __align__(16) unsigned short i12[2][NBB][IMW];
    __shared__ float hfin[NBB][32];
    __shared__ float hd[NBB][16];

    // ===== weight fragments: gate-colocated, 4 gate-tiles per MFMA wave =====
    bf16x8 wh[4][3], wl[4][3];
    f32x4  bfr[4];
    if (wid < 4){
        #pragma unroll
        for (int g = 0; g < 4; ++g){
            const float s = (g == 2) ? K2f : K1f;
            const int r = 64*g + 16*wid + bb;
            make_frags_s(&W_ih1[r*32 +      8*kg], s, wh[g][0], wl[g][0]);
            make_frags_s(&W_hh1[r*64 +      8*kg], s, wh[g][1], wl[g][1]);
            make_frags_s(&W_hh1[r*64 + 32 + 8*kg], s, wh[g][2], wl[g][2]);
            #pragma unroll
            for (int q = 0; q < 4; ++q){
                const int row = 64*g + 16*wid + 4*kg + q;
                bfr[g][q] = s * (b_ih1[row] + b_hh1[row]);
            }
        }
    } else {
        const int j = wid - 4;
        #pragma unroll
        for (int g = 0; g < 4; ++g){
            const float s = (g == 2) ? K2f : K1f;
            const int r = 32*g + 16*j + bb;
            make_frags_s(&W_ih2[r*64 +      8*kg], s, wh[g][0], wl[g][0]);
            make_frags_s(&W_ih2[r*64 + 32 + 8*kg], s, wh[g][1], wl[g][1]);
            make_frags_s(&W_hh2[r*32 +      8*kg], s, wh[g][2], wl[g][2]);
            #pragma unroll
            for (int q = 0; q < 4; ++q){
                const int row = 32*g + 16*j + 4*kg + q;
                bfr[g][q] = s * (b_ih2[row] + b_hh2[row]);
            }
        }
    }

    float cc[4] = {0.f, 0.f, 0.f, 0.f};   // c1 (L1 waves) / c2 (L2 waves)

    // x-staging on L2 waves (w4-5, 128 threads): 8 batches x 32 floats = 128 x float2
    const int xt  = tid & 127;
    const int xcb = xt >> 4;
    const int xf  = (xt & 15) * 2;
    const size_t xbase = (size_t)(b0 + xcb) * (T_*F_) + xf;
    float2 xc = make_float2(0.f, 0.f);

    // ===== init: zero image, stage x(0), preload x(1) =====
    for (int i = tid; i < 2*NBB*IMW; i += TPB) (&i12[0][0][0])[i] = 0;
    __syncthreads();
    if (wid >= 4){
        float2 x0 = *(const float2*)&x[xbase];
        *(unsigned*)&i12[0][xcb][xf] =
            (unsigned)bf16_rne(x0.x) | ((unsigned)bf16_rne(x0.y) << 16);
        xc = *(const float2*)&x[xbase + F_];
    }
    __syncthreads();

    // ===== main loop: ONE lgkm-only barrier per step (r24 schedule) =====
    for (int t = 0; t <= T_; ++t){
        const int cur = t & 1, nxt = cur ^ 1;

        if (wid < 4){
            if (t < T_){
                const unsigned short* ph = &i12[cur][0][0] + bbm*IMW + 8*kg;
                bf16x8 vh[3];
                #pragma unroll
                for (int kb = 0; kb < 3; ++kb)
                    vh[kb] = *(const bf16x8*)(ph + 32*kb);
                f32x4 a0 = bfr[0], a1 = bfr[1], a2 = bfr[2], a3 = bfr[3];
                #pragma unroll
                for (int kb = 0; kb < 3; ++kb){
                    a0 = MFMA(wh[0][kb], vh[kb], a0);
                    a1 = MFMA(wh[1][kb], vh[kb], a1);
                    a2 = MFMA(wh[2][kb], vh[kb], a2);
                    a3 = MFMA(wh[3][kb], vh[kb], a3);
                }
                #pragma unroll
                for (int kb = 0; kb < 3; ++kb){
                    a0 = MFMA(wl[0][kb], vh[kb], a0);
                    a1 = MFMA(wl[1][kb], vh[kb], a1);
                    a2 = MFMA(wl[2][kb], vh[kb], a2);
                    a3 = MFMA(wl[3][kb], vh[kb], a3);
                }
                // in-reg combine: lane owns units 16*wid+4*kg+q of batch bb (<8 real)
                ush4 HH;
                #pragma unroll
                for (int q = 0; q < 4; ++q){
                    const float h = unit_combine(a0[q], a1[q], a2[q], a3[q], cc[q]);
                    HH[q] = bf16_rne(h);
                }
                if (bb < NBB)
                    *(ush4*)&i12[nxt][bb][32 + 16*wid + 4*kg] = HH;
            }
        } else {
            // x-stage first (issue-early discipline)
            if (t + 1 < T_){
                *(unsigned*)&i12[nxt][xcb][xf] =
                    (unsigned)bf16_rne(xc.x) | ((unsigned)bf16_rne(xc.y) << 16);
                const int tn = (t + 2 < T_) ? t + 2 : T_ - 1;
                xc = *(const float2*)&x[xbase + (size_t)tn * F_];
            }
            if (t >= 1){   // compute L2(t-1)
                const unsigned short* ph = &i12[cur][0][0] + bbm*IMW + 32 + 8*kg;
                bf16x8 vh[3];
                #pragma unroll
                for (int kb = 0; kb < 3; ++kb)
                    vh[kb] = *(const bf16x8*)(ph + 32*kb);
                f32x4 a0 = bfr[0], a1 = bfr[1], a2 = bfr[2], a3 = bfr[3];
                #pragma unroll
                for (int kb = 0; kb < 3; ++kb){
                    a0 = MFMA(wh[0][kb], vh[kb], a0);
                    a1 = MFMA(wh[1][kb], vh[kb], a1);
                    a2 = MFMA(wh[2][kb], vh[kb], a2);
                    a3 = MFMA(wh[3][kb], vh[kb], a3);
                }
                #pragma unroll
                for (int kb = 0; kb < 3; ++kb){
                    a0 = MFMA(wl[0][kb], vh[kb], a0);
                    a1 = MFMA(wl[1][kb], vh[kb], a1);
                    a2 = MFMA(wl[2][kb], vh[kb], a2);
                    a3 = MFMA(wl[3][kb], vh[kb], a3);
                }
                const int j = wid - 4;
                ush4 HH;
                float hv[4];
                #pragma unroll
                for (int q = 0; q < 4; ++q){
                    hv[q] = unit_combine(a0[q], a1[q], a2[q], a3[q], cc[q]);
                    HH[q] = bf16_rne(hv[q]);
                }
                if (bb < NBB){
                    *(ush4*)&i12[nxt][bb][96 + 16*j + 4*kg] = HH;
                    if (t - 1 == T_ - 1){
                        const int u = 16*j + 4*kg;
                        hfin[bb][u]   = hv[0]; hfin[bb][u+1] = hv[1];
                        hfin[bb][u+2] = hv[2]; hfin[bb][u+3] = hv[3];
                    }
                }
            }
        }
        step_barrier();
    }

    __syncthreads();
    // ===== head: fc1(16)+relu, fc2(1) over 8 batches =====
    if (tid < NBB * 16){
        const int b = tid >> 4, j2 = tid & 15;
        float a = b_fc1[j2];
        #pragma unroll
        for (int kk = 0; kk < 32; ++kk) a = fmaf(W_fc1[j2*32 + kk], hfin[b][kk], a);
        hd[b][j2] = fmaxf(a, 0.f);
    }
    __syncthreads();
    if (tid < NBB){
        float a = b_fc2[0];
        #pragma unroll
        for (int kk = 0; kk < 16; ++kk) a = fmaf(W_fc2[kk], hd[tid][kk], a);
        out[b0 + tid] = a;
    }
}

extern "C" void kernel_launch(void* const* d_in, const int* in_sizes, int n_in,
                              void* d_out, int out_size, void* d_ws, size_t ws_size,
                              hipStream_t stream) {
    const float* x     = (const float*)d_in[0];
    const float* W_ih1 = (const float*)d_in[1];
    const float* W_hh1 = (const float*)d_in[2];
    const float* b_ih1 = (const float*)d_in[3];
    const float* b_hh1 = (const float*)d_in[4];
    const float* W_ih2 = (const float*)d_in[5];
    const float* W_hh2 = (const float*)d_in[6];
    const float* b_ih2 = (const float*)d_in[7];
    const float* b_hh2 = (const float*)d_in[8];
    const float* W_fc1 = (const float*)d_in[9];
    const float* b_fc1 = (const float*)d_in[10];
    const float* W_fc2 = (const float*)d_in[11];
    const float* b_fc2 = (const float*)d_in[12];
    float* out = (float*)d_out;

    const int B = in_sizes[0] / (T_ * F_);   // 4096
    dim3 grid(B / NBB), block(TPB);          // 512 blocks -> 2 per CU target
    hipLaunchKernelGGL(lstm_mfma, grid, block, 0, stream,
                       x, W_ih1, W_hh1, b_ih1, b_hh1,
                       W_ih2, W_hh2, b_ih2, b_hh2,
                       W_fc1, b_fc1, W_fc2, b_fc2, out);
}